// Round 5
// baseline (150.422 us; speedup 1.0000x reference)
//
#include <hip/hip_runtime.h>
#include <math.h>

namespace {

constexpr int B = 16, N = 1024, E = 32768, HEADS = 4, OC = 8;
constexpr int D_IN = 33, A_DIM = 8, DM = 16, DO = 32;
constexpr int F = D_IN + A_DIM + 1;  // 42
constexpr int CAP = 128;             // LDS-cached incoming-edge capacity per dst (deg~Poisson(32))

typedef float f4 __attribute__((ext_vector_type(4)));

__device__ __forceinline__ float lrelu(float x) { return x >= 0.f ? x : 0.2f * x; }

// ---- per-node chain ----
__global__ __launch_bounds__(64) void k_node(
    const float* __restrict__ H,
    const float* __restrict__ fc_s_w, const float* __restrict__ fc_s_b,
    const float* __restrict__ fc_a_w, const float* __restrict__ fc_a_b,
    const float* __restrict__ fc_r_w, const float* __restrict__ fc_r_b,
    const float* __restrict__ fuse_q, const float* __restrict__ fuse_k_w,
    const float* __restrict__ fuse_v_w, const float* __restrict__ proj_w,
    const float* __restrict__ proj_b, const float* __restrict__ post_w,
    const float* __restrict__ post_b, const float* __restrict__ ln_g,
    const float* __restrict__ ln_b, const float* __restrict__ gat_w,
    const float* __restrict__ att_src, const float* __restrict__ att_dst,
    float* __restrict__ x_out, float* __restrict__ as_out, float* __restrict__ advi) {
  int node = blockIdx.x * blockDim.x + threadIdx.x;
  if (node >= B * N) return;

  const float* hin = H + (size_t)node * F;
  float hv[F];
#pragma unroll
  for (int i = 0; i < F; i++) hv[i] = hin[i];

  float tok[3][DM];
#pragma unroll
  for (int j = 0; j < DM; j++) {
    float acc = fc_s_b[j];
#pragma unroll
    for (int i = 0; i < D_IN; i++) acc = fmaf(hv[i], fc_s_w[j * D_IN + i], acc);
    tok[0][j] = acc;
    float acc2 = fc_a_b[j];
#pragma unroll
    for (int i = 0; i < A_DIM; i++) acc2 = fmaf(hv[D_IN + i], fc_a_w[j * A_DIM + i], acc2);
    tok[1][j] = acc2;
    tok[2][j] = fmaf(hv[F - 1], fc_r_w[j], fc_r_b[j]);
  }

  float Kf[3][DM], Vf[3][DM];
#pragma unroll
  for (int t = 0; t < 3; t++) {
#pragma unroll
    for (int j = 0; j < DM; j++) {
      float ak = 0.f, av = 0.f;
#pragma unroll
      for (int d = 0; d < DM; d++) {
        ak = fmaf(tok[t][d], fuse_k_w[j * DM + d], ak);
        av = fmaf(tok[t][d], fuse_v_w[j * DM + d], av);
      }
      Kf[t][j] = ak; Vf[t][j] = av;
    }
  }

  float wbar[3] = {0.f, 0.f, 0.f};
#pragma unroll
  for (int q = 0; q < 3; q++) {
    float att[3];
#pragma unroll
    for (int t = 0; t < 3; t++) {
      float acc = 0.f;
#pragma unroll
      for (int d = 0; d < DM; d++) acc = fmaf(fuse_q[q * DM + d], Kf[t][d], acc);
      att[t] = acc * 0.25f;
    }
    float mx = fmaxf(att[0], fmaxf(att[1], att[2]));
    float e0 = expf(att[0] - mx), e1 = expf(att[1] - mx), e2 = expf(att[2] - mx);
    float inv = 1.f / (e0 + e1 + e2);
    wbar[0] += e0 * inv; wbar[1] += e1 * inv; wbar[2] += e2 * inv;
  }

  float fused[DM];
#pragma unroll
  for (int d = 0; d < DM; d++) {
    float f = (wbar[0] * Vf[0][d] + wbar[1] * Vf[1][d] + wbar[2] * Vf[2][d]) * (1.f / 3.f);
    fused[d] = fmaxf(f, 0.f);
  }

  float z[DO];
#pragma unroll
  for (int o = 0; o < DO; o++) {
    float acc = proj_b[o];
#pragma unroll
    for (int d = 0; d < DM; d++) acc = fmaf(fused[d], proj_w[o * DM + d], acc);
    z[o] = acc;
  }

  float h2[DO]; float mu = 0.f;
#pragma unroll
  for (int o = 0; o < DO; o++) {
    float acc = post_b[o];
#pragma unroll
    for (int d = 0; d < DO; d++) acc = fmaf(z[d], post_w[o * DO + d], acc);
    acc = fmaxf(acc, 0.f);
    h2[o] = acc; mu += acc;
  }
  mu *= (1.f / DO);
  float var = 0.f;
#pragma unroll
  for (int o = 0; o < DO; o++) { float dd = h2[o] - mu; var = fmaf(dd, dd, var); }
  var *= (1.f / DO);
  float rstd = rsqrtf(var + 1e-5f);
  float Hn[DO];
#pragma unroll
  for (int o = 0; o < DO; o++) Hn[o] = fmaf((h2[o] - mu) * rstd, ln_g[o], ln_b[o]);

  float* xrow = x_out + (size_t)node * (HEADS * OC);
  f4 asv, adv;
#pragma unroll
  for (int hh = 0; hh < HEADS; hh++) {
    float as = 0.f, ad = 0.f;
#pragma unroll
    for (int oc = 0; oc < OC; oc++) {
      int k = hh * OC + oc;
      float acc = 0.f;
#pragma unroll
      for (int d = 0; d < DO; d++) acc = fmaf(Hn[d], gat_w[k * DO + d], acc);
      xrow[k] = acc;
      as = fmaf(acc, att_src[k], as);
      ad = fmaf(acc, att_dst[k], ad);
    }
    asv[hh] = as; adv[hh] = ad;
  }
  *(f4*)(as_out + (size_t)node * HEADS) = asv;
  *(f4*)(advi + (size_t)node * 8) = adv;   // slots 0..3 = ad; 4..7 = inv (filled by k_dst)
}

// ---- CSR build: histogram ----
__global__ void k_hist(const int* __restrict__ ei, int* __restrict__ cnt_src,
                       int* __restrict__ cnt_dst) {
  int e = blockIdx.x * blockDim.x + threadIdx.x;
  if (e >= E) return;
  atomicAdd(&cnt_src[ei[e]], 1);
  atomicAdd(&cnt_dst[ei[E + e]], 1);
}

// ---- CSR build: shfl-based exclusive scan ----
__global__ __launch_bounds__(1024) void k_scan(
    const int* __restrict__ cnt_src, const int* __restrict__ cnt_dst,
    int* __restrict__ off_src, int* __restrict__ off_dst,
    int* __restrict__ cur_src, int* __restrict__ cur_dst) {
  __shared__ int ws[16];
  int t = threadIdx.x, lane = t & 63, w = t >> 6;

  {
    int v = cnt_src[t], sc = v;
#pragma unroll
    for (int o = 1; o < 64; o <<= 1) { int u = __shfl_up(sc, o); if (lane >= o) sc += u; }
    if (lane == 63) ws[w] = sc;
    __syncthreads();
    if (w == 0) {
      int x = lane < 16 ? ws[lane] : 0;
#pragma unroll
      for (int o = 1; o < 16; o <<= 1) { int u = __shfl_up(x, o); if (lane >= o) x += u; }
      if (lane < 16) ws[lane] = x;
    }
    __syncthreads();
    int inc = sc + (w ? ws[w - 1] : 0);
    off_src[t + 1] = inc;
    if (t == 0) off_src[0] = 0;
    cur_src[t] = inc - v;
    __syncthreads();
  }
  {
    int v = cnt_dst[t], sc = v;
#pragma unroll
    for (int o = 1; o < 64; o <<= 1) { int u = __shfl_up(sc, o); if (lane >= o) sc += u; }
    if (lane == 63) ws[w] = sc;
    __syncthreads();
    if (w == 0) {
      int x = lane < 16 ? ws[lane] : 0;
#pragma unroll
      for (int o = 1; o < 16; o <<= 1) { int u = __shfl_up(x, o); if (lane >= o) x += u; }
      if (lane < 16) ws[lane] = x;
    }
    __syncthreads();
    int inc = sc + (w ? ws[w - 1] : 0);
    off_dst[t + 1] = inc;
    if (t == 0) off_dst[0] = 0;
    cur_dst[t] = inc - v;
  }
}

// ---- CSR build: fill VALUE lists (store partner node id, not edge id) ----
__global__ void k_fill(const int* __restrict__ ei, int* __restrict__ cur_src,
                       int* __restrict__ cur_dst, int* __restrict__ elist_src,
                       int* __restrict__ elist_dst) {
  int e = blockIdx.x * blockDim.x + threadIdx.x;
  if (e >= E) return;
  int s = ei[e], d = ei[E + e];
  int p1 = atomicAdd(&cur_src[s], 1);
  elist_src[p1] = d;              // outgoing list holds dst ids
  int p2 = atomicAdd(&cur_dst[d], 1);
  elist_dst[p2] = s;              // incoming list holds src ids
}

// ---- per-(b,dst) softmax + out; 4 dst per block, one per wave ----
__global__ __launch_bounds__(256) void k_dst(
    const int* __restrict__ off_dst, const int* __restrict__ elist_dst,
    const float* __restrict__ as_, float* __restrict__ advi,
    const float* __restrict__ x_, const float* __restrict__ gat_b,
    float* __restrict__ out) {
  __shared__ float s_al[4][CAP][HEADS];
  __shared__ int s_src[4][CAP];
  int w = threadIdx.x >> 6, lane = threadIdx.x & 63;
  int bd = blockIdx.x * 4 + w;
  int b = bd >> 10, dn = bd & (N - 1);
  int beg = off_dst[dn];
  int deg = off_dst[dn + 1] - beg;

  f4 adv = *(const f4*)(advi + (size_t)(b * N + dn) * 8);

  float sm0 = 0.f, sm1 = 0.f, sm2 = 0.f, sm3 = 0.f;
  for (int i = lane; i < deg; i += 64) {
    int s = elist_dst[beg + i];
    f4 ap = *(const f4*)(as_ + (size_t)(b * N + s) * HEADS);
    float e0 = __expf(lrelu(ap.x + adv.x));
    float e1 = __expf(lrelu(ap.y + adv.y));
    float e2 = __expf(lrelu(ap.z + adv.z));
    float e3 = __expf(lrelu(ap.w + adv.w));
    if (i < CAP) {
      s_src[w][i] = s;
      s_al[w][i][0] = e0; s_al[w][i][1] = e1; s_al[w][i][2] = e2; s_al[w][i][3] = e3;
    }
    sm0 += e0; sm1 += e1; sm2 += e2; sm3 += e3;
  }
#pragma unroll
  for (int off = 1; off < 64; off <<= 1) {
    sm0 += __shfl_xor(sm0, off);
    sm1 += __shfl_xor(sm1, off);
    sm2 += __shfl_xor(sm2, off);
    sm3 += __shfl_xor(sm3, off);
  }
  f4 inv;
  inv.x = sm0 > 0.f ? 1.f / sm0 : 0.f;
  inv.y = sm1 > 0.f ? 1.f / sm1 : 0.f;
  inv.z = sm2 > 0.f ? 1.f / sm2 : 0.f;
  inv.w = sm3 > 0.f ? 1.f / sm3 : 0.f;
  if (lane == 0) *(f4*)(advi + (size_t)(b * N + dn) * 8 + 4) = inv;

  __syncthreads();

  // out[b,dn,c] = gat_b[c] + inv[h] * sum_e ex[e,h] * x[src,c]
  int c = lane & 31;
  int h3 = c >> 3;
  float ih  = h3 == 0 ? inv.x : h3 == 1 ? inv.y : h3 == 2 ? inv.z : inv.w;
  float adh = h3 == 0 ? adv.x : h3 == 1 ? adv.y : h3 == 2 ? adv.z : adv.w;
  float acc = 0.f;
  for (int i = (lane >> 5); i < deg; i += 2) {
    float exv; int s;
    if (i < CAP) {
      exv = s_al[w][i][h3];
      s = s_src[w][i];
    } else {
      s = elist_dst[beg + i];
      exv = __expf(lrelu(as_[(size_t)(b * N + s) * HEADS + h3] + adh));
    }
    acc = fmaf(exv, x_[(size_t)(b * N + s) * (HEADS * OC) + c], acc);
  }
  acc += __shfl_xor(acc, 32);
  if (lane < 32) out[(size_t)bd * (HEADS * OC) + c] = acc + gat_b[c] * 1.f,
                 out[(size_t)bd * (HEADS * OC) + c] = acc * ih + gat_b[c];
}

// ---- per-(b,head,src) dense A row: 4KB LDS, recompute alpha, normalize, stream ----
__global__ __launch_bounds__(256) void k_A(
    const int* __restrict__ off_src, const int* __restrict__ elist_src,
    const float* __restrict__ as_, const float* __restrict__ advi,
    float* __restrict__ A) {
  __shared__ float row[N];
  __shared__ float rsum;
  int bs = blockIdx.x;
  int s = bs & (N - 1);
  int h = (bs >> 10) & (HEADS - 1);
  int b = bs >> 12;
  int t = threadIdx.x;

  ((f4*)row)[t] = (f4){0.f, 0.f, 0.f, 0.f};
  if (t == 0) rsum = 0.f;
  __syncthreads();

  float as_h = as_[(size_t)(b * N + s) * HEADS + h];  // block-uniform
  int beg = off_src[s], end = off_src[s + 1];
  float r = 0.f;
  for (int i = beg + t; i < end; i += 256) {
    int d = elist_src[i];
    const float* rec = advi + (size_t)(b * N + d) * 8;
    float a = __expf(lrelu(as_h + rec[h])) * rec[4 + h];
    atomicAdd(&row[d], a);
    r += a;
  }
#pragma unroll
  for (int off = 1; off < 64; off <<= 1) r += __shfl_xor(r, off);
  if ((t & 63) == 0 && r != 0.f) atomicAdd(&rsum, r);
  __syncthreads();

  float ivh = 1.f / fmaxf(rsum, 1e-9f);
  f4 v = ((f4*)row)[t];
  v.x *= ivh; v.y *= ivh; v.z *= ivh; v.w *= ivh;
  f4* dst = (f4*)(A + (((size_t)b * HEADS + h) * N + s) * N) + t;
  __builtin_nontemporal_store(v, dst);
}

}  // namespace

extern "C" void kernel_launch(void* const* d_in, const int* in_sizes, int n_in,
                              void* d_out, int out_size, void* d_ws, size_t ws_size,
                              hipStream_t stream) {
  const float* H      = (const float*)d_in[0];
  const int*   ei     = (const int*)  d_in[1];
  const float* fc_s_w = (const float*)d_in[2];
  const float* fc_s_b = (const float*)d_in[3];
  const float* fc_a_w = (const float*)d_in[4];
  const float* fc_a_b = (const float*)d_in[5];
  const float* fc_r_w = (const float*)d_in[6];
  const float* fc_r_b = (const float*)d_in[7];
  const float* fuse_q = (const float*)d_in[8];
  const float* fuse_k_w = (const float*)d_in[9];
  const float* fuse_v_w = (const float*)d_in[10];
  const float* proj_w = (const float*)d_in[11];
  const float* proj_b = (const float*)d_in[12];
  const float* post_w = (const float*)d_in[13];
  const float* post_b = (const float*)d_in[14];
  const float* ln_g   = (const float*)d_in[15];
  const float* ln_b   = (const float*)d_in[16];
  const float* gat_w  = (const float*)d_in[17];
  const float* att_src = (const float*)d_in[18];
  const float* att_dst = (const float*)d_in[19];
  const float* gat_b  = (const float*)d_in[20];

  float* out = (float*)d_out;                        // (B,N,32)
  float* A   = out + (size_t)B * N * DO;             // (B,4,N,N)

  // ws layout
  float* ws   = (float*)d_ws;
  float* xbuf = ws;                                  // B*N*32
  float* asb  = xbuf + (size_t)B * N * (HEADS * OC); // B*N*4
  float* advi = asb + (size_t)B * N * HEADS;         // B*N*8 (ad 0..3 | inv 4..7)
  int* ibase     = (int*)(advi + (size_t)B * N * 8);
  int* cnt_src   = ibase;            // 1024
  int* cnt_dst   = cnt_src + N;      // 1024
  int* off_src   = cnt_dst + N;      // 1025
  int* off_dst   = off_src + (N + 1);
  int* cur_src   = off_dst + (N + 1);
  int* cur_dst   = cur_src + N;
  int* elist_src = cur_dst + N;      // E (dst ids)
  int* elist_dst = elist_src + E;    // E (src ids)

  (void)hipMemsetAsync(cnt_src, 0, 2 * N * sizeof(int), stream);
  k_hist<<<dim3(E / 256), dim3(256), 0, stream>>>(ei, cnt_src, cnt_dst);
  k_scan<<<dim3(1), dim3(N), 0, stream>>>(cnt_src, cnt_dst, off_src, off_dst, cur_src, cur_dst);
  k_fill<<<dim3(E / 256), dim3(256), 0, stream>>>(ei, cur_src, cur_dst, elist_src, elist_dst);

  k_node<<<dim3((B * N) / 64), dim3(64), 0, stream>>>(
      H, fc_s_w, fc_s_b, fc_a_w, fc_a_b, fc_r_w, fc_r_b, fuse_q, fuse_k_w,
      fuse_v_w, proj_w, proj_b, post_w, post_b, ln_g, ln_b, gat_w, att_src,
      att_dst, xbuf, asb, advi);

  k_dst<<<dim3(B * N / 4), dim3(256), 0, stream>>>(off_dst, elist_dst, asb, advi,
                                                   xbuf, gat_b, out);
  k_A<<<dim3(B * N * HEADS), dim3(256), 0, stream>>>(off_src, elist_src, asb, advi, A);
}

// Round 7
// 132.222 us; speedup vs baseline: 1.1377x; 1.1377x over previous
//
#include <hip/hip_runtime.h>
#include <math.h>

namespace {

constexpr int B = 16, N = 1024, E = 32768, HEADS = 4, OC = 8;
constexpr int D_IN = 33, A_DIM = 8, DM = 16, DO = 32;
constexpr int F = D_IN + A_DIM + 1;  // 42
constexpr int CAP = 128;   // LDS cache cap in k_dst (realized max deg ~65)
constexpr int BCAP = 256;  // fixed bucket capacity (P(deg>=256) ~ 0 for Poisson(32))

typedef float f4 __attribute__((ext_vector_type(4)));

__device__ __forceinline__ float lrelu(float x) { return x >= 0.f ? x : 0.2f * x; }

// ---- per-node chain ----
__global__ __launch_bounds__(64) void k_node(
    const float* __restrict__ H,
    const float* __restrict__ fc_s_w, const float* __restrict__ fc_s_b,
    const float* __restrict__ fc_a_w, const float* __restrict__ fc_a_b,
    const float* __restrict__ fc_r_w, const float* __restrict__ fc_r_b,
    const float* __restrict__ fuse_q, const float* __restrict__ fuse_k_w,
    const float* __restrict__ fuse_v_w, const float* __restrict__ proj_w,
    const float* __restrict__ proj_b, const float* __restrict__ post_w,
    const float* __restrict__ post_b, const float* __restrict__ ln_g,
    const float* __restrict__ ln_b, const float* __restrict__ gat_w,
    const float* __restrict__ att_src, const float* __restrict__ att_dst,
    float* __restrict__ x_out, float* __restrict__ as_out, float* __restrict__ advi) {
  int node = blockIdx.x * blockDim.x + threadIdx.x;
  if (node >= B * N) return;

  const float* hin = H + (size_t)node * F;
  float hv[F];
#pragma unroll
  for (int i = 0; i < F; i++) hv[i] = hin[i];

  float tok[3][DM];
#pragma unroll
  for (int j = 0; j < DM; j++) {
    float acc = fc_s_b[j];
#pragma unroll
    for (int i = 0; i < D_IN; i++) acc = fmaf(hv[i], fc_s_w[j * D_IN + i], acc);
    tok[0][j] = acc;
    float acc2 = fc_a_b[j];
#pragma unroll
    for (int i = 0; i < A_DIM; i++) acc2 = fmaf(hv[D_IN + i], fc_a_w[j * A_DIM + i], acc2);
    tok[1][j] = acc2;
    tok[2][j] = fmaf(hv[F - 1], fc_r_w[j], fc_r_b[j]);
  }

  float Kf[3][DM], Vf[3][DM];
#pragma unroll
  for (int t = 0; t < 3; t++) {
#pragma unroll
    for (int j = 0; j < DM; j++) {
      float ak = 0.f, av = 0.f;
#pragma unroll
      for (int d = 0; d < DM; d++) {
        ak = fmaf(tok[t][d], fuse_k_w[j * DM + d], ak);
        av = fmaf(tok[t][d], fuse_v_w[j * DM + d], av);
      }
      Kf[t][j] = ak; Vf[t][j] = av;
    }
  }

  float wbar[3] = {0.f, 0.f, 0.f};
#pragma unroll
  for (int q = 0; q < 3; q++) {
    float att[3];
#pragma unroll
    for (int t = 0; t < 3; t++) {
      float acc = 0.f;
#pragma unroll
      for (int d = 0; d < DM; d++) acc = fmaf(fuse_q[q * DM + d], Kf[t][d], acc);
      att[t] = acc * 0.25f;
    }
    float mx = fmaxf(att[0], fmaxf(att[1], att[2]));
    float e0 = expf(att[0] - mx), e1 = expf(att[1] - mx), e2 = expf(att[2] - mx);
    float inv = 1.f / (e0 + e1 + e2);
    wbar[0] += e0 * inv; wbar[1] += e1 * inv; wbar[2] += e2 * inv;
  }

  float fused[DM];
#pragma unroll
  for (int d = 0; d < DM; d++) {
    float f = (wbar[0] * Vf[0][d] + wbar[1] * Vf[1][d] + wbar[2] * Vf[2][d]) * (1.f / 3.f);
    fused[d] = fmaxf(f, 0.f);
  }

  float z[DO];
#pragma unroll
  for (int o = 0; o < DO; o++) {
    float acc = proj_b[o];
#pragma unroll
    for (int d = 0; d < DM; d++) acc = fmaf(fused[d], proj_w[o * DM + d], acc);
    z[o] = acc;
  }

  float h2[DO]; float mu = 0.f;
#pragma unroll
  for (int o = 0; o < DO; o++) {
    float acc = post_b[o];
#pragma unroll
    for (int d = 0; d < DO; d++) acc = fmaf(z[d], post_w[o * DO + d], acc);
    acc = fmaxf(acc, 0.f);
    h2[o] = acc; mu += acc;
  }
  mu *= (1.f / DO);
  float var = 0.f;
#pragma unroll
  for (int o = 0; o < DO; o++) { float dd = h2[o] - mu; var = fmaf(dd, dd, var); }
  var *= (1.f / DO);
  float rstd = rsqrtf(var + 1e-5f);
  float Hn[DO];
#pragma unroll
  for (int o = 0; o < DO; o++) Hn[o] = fmaf((h2[o] - mu) * rstd, ln_g[o], ln_b[o]);

  float* xrow = x_out + (size_t)node * (HEADS * OC);
  f4 asv, adv;
#pragma unroll
  for (int hh = 0; hh < HEADS; hh++) {
    float as = 0.f, ad = 0.f;
#pragma unroll
    for (int oc = 0; oc < OC; oc++) {
      int k = hh * OC + oc;
      float acc = 0.f;
#pragma unroll
      for (int d = 0; d < DO; d++) acc = fmaf(Hn[d], gat_w[k * DO + d], acc);
      xrow[k] = acc;
      as = fmaf(acc, att_src[k], as);
      ad = fmaf(acc, att_dst[k], ad);
    }
    asv[hh] = as; adv[hh] = ad;
  }
  *(f4*)(as_out + (size_t)node * HEADS) = asv;
  *(f4*)(advi + (size_t)node * 8) = adv;   // slots 0..3 = ad; 4..7 = inv (filled by k_dst)
}

// ---- bucket fill: fixed-capacity per-node adjacency ----
__global__ void k_fill(const int* __restrict__ ei, int* __restrict__ cnt_src,
                       int* __restrict__ cnt_dst, int* __restrict__ bkt_src,
                       int* __restrict__ bkt_dst) {
  int e = blockIdx.x * blockDim.x + threadIdx.x;
  if (e >= E) return;
  int s = ei[e], d = ei[E + e];
  int p1 = atomicAdd(&cnt_src[s], 1);
  if (p1 < BCAP) bkt_src[s * BCAP + p1] = d;   // outgoing: dst ids
  int p2 = atomicAdd(&cnt_dst[d], 1);
  if (p2 < BCAP) bkt_dst[d * BCAP + p2] = s;   // incoming: src ids
}

// ---- per-(b,dst) softmax + out; 4 dst per block, one per wave ----
__global__ __launch_bounds__(256) void k_dst(
    const int* __restrict__ cnt_dst, const int* __restrict__ bkt_dst,
    const float* __restrict__ as_, float* __restrict__ advi,
    const float* __restrict__ x_, const float* __restrict__ gat_b,
    float* __restrict__ out) {
  __shared__ float s_al[4][CAP][HEADS];
  __shared__ int s_src[4][CAP];
  int w = threadIdx.x >> 6, lane = threadIdx.x & 63;
  int bd = blockIdx.x * 4 + w;
  int b = bd >> 10, dn = bd & (N - 1);
  int deg = min(cnt_dst[dn], BCAP);
  const int* list = bkt_dst + dn * BCAP;

  f4 adv = *(const f4*)(advi + (size_t)(b * N + dn) * 8);

  float sm0 = 0.f, sm1 = 0.f, sm2 = 0.f, sm3 = 0.f;
  for (int i = lane; i < deg; i += 64) {
    int s = list[i];
    f4 ap = *(const f4*)(as_ + (size_t)(b * N + s) * HEADS);
    float e0 = __expf(lrelu(ap.x + adv.x));
    float e1 = __expf(lrelu(ap.y + adv.y));
    float e2 = __expf(lrelu(ap.z + adv.z));
    float e3 = __expf(lrelu(ap.w + adv.w));
    if (i < CAP) {
      s_src[w][i] = s;
      s_al[w][i][0] = e0; s_al[w][i][1] = e1; s_al[w][i][2] = e2; s_al[w][i][3] = e3;
    }
    sm0 += e0; sm1 += e1; sm2 += e2; sm3 += e3;
  }
#pragma unroll
  for (int off = 1; off < 64; off <<= 1) {
    sm0 += __shfl_xor(sm0, off);
    sm1 += __shfl_xor(sm1, off);
    sm2 += __shfl_xor(sm2, off);
    sm3 += __shfl_xor(sm3, off);
  }
  f4 inv;
  inv.x = sm0 > 0.f ? 1.f / sm0 : 0.f;
  inv.y = sm1 > 0.f ? 1.f / sm1 : 0.f;
  inv.z = sm2 > 0.f ? 1.f / sm2 : 0.f;
  inv.w = sm3 > 0.f ? 1.f / sm3 : 0.f;
  if (lane == 0) *(f4*)(advi + (size_t)(b * N + dn) * 8 + 4) = inv;

  __syncthreads();  // defensive: separate LDS cache-fill from reuse

  int c = lane & 31;
  int h3 = c >> 3;
  float ih  = h3 == 0 ? inv.x : h3 == 1 ? inv.y : h3 == 2 ? inv.z : inv.w;
  float adh = h3 == 0 ? adv.x : h3 == 1 ? adv.y : h3 == 2 ? adv.z : adv.w;
  float acc = 0.f;
  for (int i = (lane >> 5); i < deg; i += 2) {
    float exv; int s;
    if (i < CAP) {
      exv = s_al[w][i][h3];
      s = s_src[w][i];
    } else {
      s = list[i];
      exv = __expf(lrelu(as_[(size_t)(b * N + s) * HEADS + h3] + adh));
    }
    acc = fmaf(exv, x_[(size_t)(b * N + s) * (HEADS * OC) + c], acc);
  }
  acc += __shfl_xor(acc, 32);
  if (lane < 32) out[(size_t)bd * (HEADS * OC) + c] = acc * ih + gat_b[c];
}

// ---- per-(b,src) dense A rows: 4 waves = 4 heads; barriers around LDS-atomic phase ----
// LESSON (R6): no-return DS atomics are NOT reliably ordered with subsequent
// same-wave ds_reads without an explicit barrier/waitcnt. Plain st/ld is fine.
__global__ __launch_bounds__(256) void k_A(
    const int* __restrict__ cnt_src, const int* __restrict__ bkt_src,
    const float* __restrict__ as_, const float* __restrict__ advi,
    float* __restrict__ A) {
  __shared__ float row[HEADS][N];
  int bs = blockIdx.x;
  int s = bs & (N - 1);
  int b = bs >> 10;
  int h = threadIdx.x >> 6, lane = threadIdx.x & 63;

  f4* rowv = (f4*)row[h];
#pragma unroll
  for (int j = 0; j < 4; j++) rowv[lane + j * 64] = (f4){0.f, 0.f, 0.f, 0.f};
  __syncthreads();

  float as_h = as_[(size_t)(b * N + s) * HEADS + h];  // wave-uniform
  int deg = min(cnt_src[s], BCAP);
  const int* list = bkt_src + s * BCAP;
  float r = 0.f;
  for (int i = lane; i < deg; i += 64) {
    int d = list[i];
    const float* rec = advi + (size_t)(b * N + d) * 8;
    float a = __expf(lrelu(as_h + rec[h])) * rec[4 + h];
    atomicAdd(&row[h][d], a);
    r += a;
  }
#pragma unroll
  for (int off = 1; off < 64; off <<= 1) r += __shfl_xor(r, off);
  __syncthreads();  // REQUIRED: flush DS atomics before reading the row

  float ivh = 1.f / fmaxf(r, 1e-9f);
  float* Arow = A + (((size_t)b * HEADS + h) * N + s) * N;
#pragma unroll
  for (int j = 0; j < 4; j++) {
    f4 v = rowv[lane + j * 64];
    v.x *= ivh; v.y *= ivh; v.z *= ivh; v.w *= ivh;
    __builtin_nontemporal_store(v, (f4*)Arow + lane + j * 64);
  }
}

}  // namespace

extern "C" void kernel_launch(void* const* d_in, const int* in_sizes, int n_in,
                              void* d_out, int out_size, void* d_ws, size_t ws_size,
                              hipStream_t stream) {
  const float* H      = (const float*)d_in[0];
  const int*   ei     = (const int*)  d_in[1];
  const float* fc_s_w = (const float*)d_in[2];
  const float* fc_s_b = (const float*)d_in[3];
  const float* fc_a_w = (const float*)d_in[4];
  const float* fc_a_b = (const float*)d_in[5];
  const float* fc_r_w = (const float*)d_in[6];
  const float* fc_r_b = (const float*)d_in[7];
  const float* fuse_q = (const float*)d_in[8];
  const float* fuse_k_w = (const float*)d_in[9];
  const float* fuse_v_w = (const float*)d_in[10];
  const float* proj_w = (const float*)d_in[11];
  const float* proj_b = (const float*)d_in[12];
  const float* post_w = (const float*)d_in[13];
  const float* post_b = (const float*)d_in[14];
  const float* ln_g   = (const float*)d_in[15];
  const float* ln_b   = (const float*)d_in[16];
  const float* gat_w  = (const float*)d_in[17];
  const float* att_src = (const float*)d_in[18];
  const float* att_dst = (const float*)d_in[19];
  const float* gat_b  = (const float*)d_in[20];

  float* out = (float*)d_out;                        // (B,N,32)
  float* A   = out + (size_t)B * N * DO;             // (B,4,N,N)

  // ws layout
  float* ws   = (float*)d_ws;
  float* xbuf = ws;                                  // B*N*32
  float* asb  = xbuf + (size_t)B * N * (HEADS * OC); // B*N*4
  float* advi = asb + (size_t)B * N * HEADS;         // B*N*8 (ad 0..3 | inv 4..7)
  int* ibase   = (int*)(advi + (size_t)B * N * 8);
  int* cnt_src = ibase;                 // N
  int* cnt_dst = cnt_src + N;           // N
  int* bkt_src = cnt_dst + N;           // N*BCAP (dst ids per src)
  int* bkt_dst = bkt_src + N * BCAP;    // N*BCAP (src ids per dst)

  (void)hipMemsetAsync(cnt_src, 0, 2 * N * sizeof(int), stream);
  k_fill<<<dim3(E / 256), dim3(256), 0, stream>>>(ei, cnt_src, cnt_dst, bkt_src, bkt_dst);

  k_node<<<dim3((B * N) / 64), dim3(64), 0, stream>>>(
      H, fc_s_w, fc_s_b, fc_a_w, fc_a_b, fc_r_w, fc_r_b, fuse_q, fuse_k_w,
      fuse_v_w, proj_w, proj_b, post_w, post_b, ln_g, ln_b, gat_w, att_src,
      att_dst, xbuf, asb, advi);

  k_dst<<<dim3(B * N / 4), dim3(256), 0, stream>>>(cnt_dst, bkt_dst, asb, advi,
                                                   xbuf, gat_b, out);
  k_A<<<dim3(B * N), dim3(256), 0, stream>>>(cnt_src, bkt_src, asb, advi, A);
}

// Round 8
// 118.537 us; speedup vs baseline: 1.2690x; 1.1154x over previous
//
#include <hip/hip_runtime.h>
#include <math.h>

namespace {

constexpr int B = 16, N = 1024, E = 32768, HEADS = 4, OC = 8;
constexpr int D_IN = 33, A_DIM = 8, DM = 16, DO = 32;
constexpr int F = D_IN + A_DIM + 1;  // 42
constexpr int BCAP = 256;   // fixed bucket capacity (realized max deg ~65, Poisson(32))
constexpr int FILLB = E / 256;  // 128 fill blocks in k_prep

typedef float f4 __attribute__((ext_vector_type(4)));

__device__ __forceinline__ float lrelu(float x) { return x >= 0.f ? x : 0.2f * x; }

// ---- fused: bucket fill (blocks [0,FILLB)) + per-node chain (rest) ----
__global__ __launch_bounds__(256) void k_prep(
    const int* __restrict__ ei, int* __restrict__ cnt_src,
    int* __restrict__ cnt_dst, int* __restrict__ bkt_src,
    int* __restrict__ bkt_dst,
    const float* __restrict__ H,
    const float* __restrict__ fc_s_w, const float* __restrict__ fc_s_b,
    const float* __restrict__ fc_a_w, const float* __restrict__ fc_a_b,
    const float* __restrict__ fc_r_w, const float* __restrict__ fc_r_b,
    const float* __restrict__ fuse_q, const float* __restrict__ fuse_k_w,
    const float* __restrict__ fuse_v_w, const float* __restrict__ proj_w,
    const float* __restrict__ proj_b, const float* __restrict__ post_w,
    const float* __restrict__ post_b, const float* __restrict__ ln_g,
    const float* __restrict__ ln_b, const float* __restrict__ gat_w,
    const float* __restrict__ att_src, const float* __restrict__ att_dst,
    float* __restrict__ x_out, float* __restrict__ as_out, float* __restrict__ advi) {
  if (blockIdx.x < FILLB) {
    int e = blockIdx.x * 256 + threadIdx.x;
    int s = ei[e], d = ei[E + e];
    int p1 = atomicAdd(&cnt_src[s], 1);
    if (p1 < BCAP) bkt_src[s * BCAP + p1] = d;   // outgoing: dst ids
    int p2 = atomicAdd(&cnt_dst[d], 1);
    if (p2 < BCAP) bkt_dst[d * BCAP + p2] = s;   // incoming: src ids
    return;
  }
  int node = (blockIdx.x - FILLB) * 256 + threadIdx.x;
  if (node >= B * N) return;

  const float* hin = H + (size_t)node * F;
  float hv[F];
#pragma unroll
  for (int i = 0; i < F; i++) hv[i] = hin[i];

  float tok[3][DM];
#pragma unroll
  for (int j = 0; j < DM; j++) {
    float acc = fc_s_b[j];
#pragma unroll
    for (int i = 0; i < D_IN; i++) acc = fmaf(hv[i], fc_s_w[j * D_IN + i], acc);
    tok[0][j] = acc;
    float acc2 = fc_a_b[j];
#pragma unroll
    for (int i = 0; i < A_DIM; i++) acc2 = fmaf(hv[D_IN + i], fc_a_w[j * A_DIM + i], acc2);
    tok[1][j] = acc2;
    tok[2][j] = fmaf(hv[F - 1], fc_r_w[j], fc_r_b[j]);
  }

  float Kf[3][DM], Vf[3][DM];
#pragma unroll
  for (int t = 0; t < 3; t++) {
#pragma unroll
    for (int j = 0; j < DM; j++) {
      float ak = 0.f, av = 0.f;
#pragma unroll
      for (int d = 0; d < DM; d++) {
        ak = fmaf(tok[t][d], fuse_k_w[j * DM + d], ak);
        av = fmaf(tok[t][d], fuse_v_w[j * DM + d], av);
      }
      Kf[t][j] = ak; Vf[t][j] = av;
    }
  }

  float wbar[3] = {0.f, 0.f, 0.f};
#pragma unroll
  for (int q = 0; q < 3; q++) {
    float att[3];
#pragma unroll
    for (int t = 0; t < 3; t++) {
      float acc = 0.f;
#pragma unroll
      for (int d = 0; d < DM; d++) acc = fmaf(fuse_q[q * DM + d], Kf[t][d], acc);
      att[t] = acc * 0.25f;
    }
    float mx = fmaxf(att[0], fmaxf(att[1], att[2]));
    float e0 = expf(att[0] - mx), e1 = expf(att[1] - mx), e2 = expf(att[2] - mx);
    float inv = 1.f / (e0 + e1 + e2);
    wbar[0] += e0 * inv; wbar[1] += e1 * inv; wbar[2] += e2 * inv;
  }

  float fused[DM];
#pragma unroll
  for (int d = 0; d < DM; d++) {
    float f = (wbar[0] * Vf[0][d] + wbar[1] * Vf[1][d] + wbar[2] * Vf[2][d]) * (1.f / 3.f);
    fused[d] = fmaxf(f, 0.f);
  }

  float z[DO];
#pragma unroll
  for (int o = 0; o < DO; o++) {
    float acc = proj_b[o];
#pragma unroll
    for (int d = 0; d < DM; d++) acc = fmaf(fused[d], proj_w[o * DM + d], acc);
    z[o] = acc;
  }

  float h2[DO]; float mu = 0.f;
#pragma unroll
  for (int o = 0; o < DO; o++) {
    float acc = post_b[o];
#pragma unroll
    for (int d = 0; d < DO; d++) acc = fmaf(z[d], post_w[o * DO + d], acc);
    acc = fmaxf(acc, 0.f);
    h2[o] = acc; mu += acc;
  }
  mu *= (1.f / DO);
  float var = 0.f;
#pragma unroll
  for (int o = 0; o < DO; o++) { float dd = h2[o] - mu; var = fmaf(dd, dd, var); }
  var *= (1.f / DO);
  float rstd = rsqrtf(var + 1e-5f);
  float Hn[DO];
#pragma unroll
  for (int o = 0; o < DO; o++) Hn[o] = fmaf((h2[o] - mu) * rstd, ln_g[o], ln_b[o]);

  float* xrow = x_out + (size_t)node * (HEADS * OC);
  f4 asv, adv;
#pragma unroll
  for (int hh = 0; hh < HEADS; hh++) {
    float as = 0.f, ad = 0.f;
#pragma unroll
    for (int oc = 0; oc < OC; oc++) {
      int k = hh * OC + oc;
      float acc = 0.f;
#pragma unroll
      for (int d = 0; d < DO; d++) acc = fmaf(Hn[d], gat_w[k * DO + d], acc);
      xrow[k] = acc;
      as = fmaf(acc, att_src[k], as);
      ad = fmaf(acc, att_dst[k], ad);
    }
    asv[hh] = as; adv[hh] = ad;
  }
  *(f4*)(as_out + (size_t)node * HEADS) = asv;
  *(f4*)(advi + (size_t)node * 8) = adv;   // slots 0..3 = ad; 4..7 = inv (k_inv)
}

// ---- per-(b,dst) softmax denominator only; 4 dst per block, one per wave ----
__global__ __launch_bounds__(256) void k_inv(
    const int* __restrict__ cnt_dst, const int* __restrict__ bkt_dst,
    const float* __restrict__ as_, float* __restrict__ advi) {
  int w = threadIdx.x >> 6, lane = threadIdx.x & 63;
  int bd = blockIdx.x * 4 + w;
  int b = bd >> 10, dn = bd & (N - 1);
  int deg = min(cnt_dst[dn], BCAP);
  const int* list = bkt_dst + dn * BCAP;

  f4 adv = *(const f4*)(advi + (size_t)(b * N + dn) * 8);

  float sm0 = 0.f, sm1 = 0.f, sm2 = 0.f, sm3 = 0.f;
  for (int i = lane; i < deg; i += 64) {
    int s = list[i];
    f4 ap = *(const f4*)(as_ + (size_t)(b * N + s) * HEADS);
    sm0 += __expf(lrelu(ap.x + adv.x));
    sm1 += __expf(lrelu(ap.y + adv.y));
    sm2 += __expf(lrelu(ap.z + adv.z));
    sm3 += __expf(lrelu(ap.w + adv.w));
  }
#pragma unroll
  for (int off = 1; off < 64; off <<= 1) {
    sm0 += __shfl_xor(sm0, off);
    sm1 += __shfl_xor(sm1, off);
    sm2 += __shfl_xor(sm2, off);
    sm3 += __shfl_xor(sm3, off);
  }
  f4 inv;
  inv.x = sm0 > 0.f ? 1.f / sm0 : 0.f;
  inv.y = sm1 > 0.f ? 1.f / sm1 : 0.f;
  inv.z = sm2 > 0.f ? 1.f / sm2 : 0.f;
  inv.w = sm3 > 0.f ? 1.f / sm3 : 0.f;
  if (lane == 0) *(f4*)(advi + (size_t)(b * N + dn) * 8 + 4) = inv;
}

// ---- fused per-(b,n): A rows (n as src; 4 waves = 4 heads) + out row (n as dst) ----
// LESSON (R6): no-return DS atomics are NOT ordered with subsequent ds_reads
// without an explicit barrier. Plain st/ld is fine barrier-free.
__global__ __launch_bounds__(256) void k_outA(
    const int* __restrict__ cnt_src, const int* __restrict__ bkt_src,
    const int* __restrict__ cnt_dst, const int* __restrict__ bkt_dst,
    const float* __restrict__ as_, const float* __restrict__ advi,
    const float* __restrict__ x_, const float* __restrict__ gat_b,
    float* __restrict__ out, float* __restrict__ A) {
  __shared__ float row[HEADS][N];
  int bs = blockIdx.x;
  int s = bs & (N - 1);
  int b = bs >> 10;
  int h = threadIdx.x >> 6, lane = threadIdx.x & 63;

  f4* rowv = (f4*)row[h];
#pragma unroll
  for (int j = 0; j < 4; j++) rowv[lane + j * 64] = (f4){0.f, 0.f, 0.f, 0.f};
  __syncthreads();

  // A accumulate over out-edges of s
  float as_h = as_[(size_t)(b * N + s) * HEADS + h];  // wave-uniform
  int degO = min(cnt_src[s], BCAP);
  const int* listO = bkt_src + s * BCAP;
  float r = 0.f;
  for (int i = lane; i < degO; i += 64) {
    int d = listO[i];
    const float* rec = advi + (size_t)(b * N + d) * 8;
    float a = __expf(lrelu(as_h + rec[h])) * rec[4 + h];
    atomicAdd(&row[h][d], a);
    r += a;
  }
#pragma unroll
  for (int off = 1; off < 64; off <<= 1) r += __shfl_xor(r, off);

  // out row for node s (as dst), channels c = 8h + (lane&7); hides under A phase
  {
    int degI = min(cnt_dst[s], BCAP);
    const int* listI = bkt_dst + s * BCAP;
    float adh = advi[(size_t)(b * N + s) * 8 + h];
    float ivh = advi[(size_t)(b * N + s) * 8 + 4 + h];
    int eslot = lane >> 3, cl = lane & 7, c = h * OC + cl;
    float acc = 0.f;
    for (int i = eslot; i < degI; i += 8) {
      int src = listI[i];
      float ex = __expf(lrelu(as_[(size_t)(b * N + src) * HEADS + h] + adh));
      acc = fmaf(ex, x_[(size_t)(b * N + src) * (HEADS * OC) + c], acc);
    }
    acc += __shfl_xor(acc, 8);
    acc += __shfl_xor(acc, 16);
    acc += __shfl_xor(acc, 32);
    if (eslot == 0)
      out[(size_t)bs * (HEADS * OC) + c] = acc * ivh + gat_b[c];
  }

  __syncthreads();  // REQUIRED: flush DS atomics before reading the row

  float ivr = 1.f / fmaxf(r, 1e-9f);
  float* Arow = A + (((size_t)b * HEADS + h) * N + s) * N;
#pragma unroll
  for (int j = 0; j < 4; j++) {
    f4 v = rowv[lane + j * 64];
    v.x *= ivr; v.y *= ivr; v.z *= ivr; v.w *= ivr;
    __builtin_nontemporal_store(v, (f4*)Arow + lane + j * 64);
  }
}

}  // namespace

extern "C" void kernel_launch(void* const* d_in, const int* in_sizes, int n_in,
                              void* d_out, int out_size, void* d_ws, size_t ws_size,
                              hipStream_t stream) {
  const float* H      = (const float*)d_in[0];
  const int*   ei     = (const int*)  d_in[1];
  const float* fc_s_w = (const float*)d_in[2];
  const float* fc_s_b = (const float*)d_in[3];
  const float* fc_a_w = (const float*)d_in[4];
  const float* fc_a_b = (const float*)d_in[5];
  const float* fc_r_w = (const float*)d_in[6];
  const float* fc_r_b = (const float*)d_in[7];
  const float* fuse_q = (const float*)d_in[8];
  const float* fuse_k_w = (const float*)d_in[9];
  const float* fuse_v_w = (const float*)d_in[10];
  const float* proj_w = (const float*)d_in[11];
  const float* proj_b = (const float*)d_in[12];
  const float* post_w = (const float*)d_in[13];
  const float* post_b = (const float*)d_in[14];
  const float* ln_g   = (const float*)d_in[15];
  const float* ln_b   = (const float*)d_in[16];
  const float* gat_w  = (const float*)d_in[17];
  const float* att_src = (const float*)d_in[18];
  const float* att_dst = (const float*)d_in[19];
  const float* gat_b  = (const float*)d_in[20];

  float* out = (float*)d_out;                        // (B,N,32)
  float* A   = out + (size_t)B * N * DO;             // (B,4,N,N)

  // ws layout
  float* ws   = (float*)d_ws;
  float* xbuf = ws;                                  // B*N*32
  float* asb  = xbuf + (size_t)B * N * (HEADS * OC); // B*N*4
  float* advi = asb + (size_t)B * N * HEADS;         // B*N*8 (ad 0..3 | inv 4..7)
  int* ibase   = (int*)(advi + (size_t)B * N * 8);
  int* cnt_src = ibase;                 // N
  int* cnt_dst = cnt_src + N;           // N
  int* bkt_src = cnt_dst + N;           // N*BCAP (dst ids per src)
  int* bkt_dst = bkt_src + N * BCAP;    // N*BCAP (src ids per dst)

  (void)hipMemsetAsync(cnt_src, 0, 2 * N * sizeof(int), stream);
  k_prep<<<dim3(FILLB + (B * N) / 256), dim3(256), 0, stream>>>(
      ei, cnt_src, cnt_dst, bkt_src, bkt_dst,
      H, fc_s_w, fc_s_b, fc_a_w, fc_a_b, fc_r_w, fc_r_b, fuse_q, fuse_k_w,
      fuse_v_w, proj_w, proj_b, post_w, post_b, ln_g, ln_b, gat_w, att_src,
      att_dst, xbuf, asb, advi);

  k_inv<<<dim3(B * N / 4), dim3(256), 0, stream>>>(cnt_dst, bkt_dst, asb, advi);

  k_outA<<<dim3(B * N), dim3(256), 0, stream>>>(cnt_src, bkt_src, cnt_dst, bkt_dst,
                                                asb, advi, xbuf, gat_b, out, A);
}

// Round 9
// 106.539 us; speedup vs baseline: 1.4119x; 1.1126x over previous
//
#include <hip/hip_runtime.h>
#include <math.h>

namespace {

constexpr int B = 16, N = 1024, E = 32768, HEADS = 4, OC = 8;
constexpr int D_IN = 33, A_DIM = 8, DM = 16, DO = 32;
constexpr int F = D_IN + A_DIM + 1;  // 42
constexpr int BCAP = 256;        // fixed bucket capacity (realized max deg ~65, Poisson(32))
constexpr int FILLB = E / 256;   // 128 fill blocks in k_prep
constexpr int ROWS_PER_BLK = 8;  // k_outA grid-stride rows per block

typedef float f4 __attribute__((ext_vector_type(4)));
typedef float f2 __attribute__((ext_vector_type(2)));

__device__ __forceinline__ float lrelu(float x) { return x >= 0.f ? x : 0.2f * x; }

// advi layout: advi[node*8 + 2*h + 0] = ad_h ; advi[node*8 + 2*h + 1] = inv_h

// ---- fused: bucket fill (blocks [0,FILLB)) + per-node chain (rest) ----
__global__ __launch_bounds__(256) void k_prep(
    const int* __restrict__ ei, int* __restrict__ cnt_src,
    int* __restrict__ cnt_dst, int* __restrict__ bkt_src,
    int* __restrict__ bkt_dst,
    const float* __restrict__ H,
    const float* __restrict__ fc_s_w, const float* __restrict__ fc_s_b,
    const float* __restrict__ fc_a_w, const float* __restrict__ fc_a_b,
    const float* __restrict__ fc_r_w, const float* __restrict__ fc_r_b,
    const float* __restrict__ fuse_q, const float* __restrict__ fuse_k_w,
    const float* __restrict__ fuse_v_w, const float* __restrict__ proj_w,
    const float* __restrict__ proj_b, const float* __restrict__ post_w,
    const float* __restrict__ post_b, const float* __restrict__ ln_g,
    const float* __restrict__ ln_b, const float* __restrict__ gat_w,
    const float* __restrict__ att_src, const float* __restrict__ att_dst,
    float* __restrict__ x_out, float* __restrict__ as_out, float* __restrict__ advi) {
  if (blockIdx.x < FILLB) {
    int e = blockIdx.x * 256 + threadIdx.x;
    int s = ei[e], d = ei[E + e];
    int p1 = atomicAdd(&cnt_src[s], 1);
    if (p1 < BCAP) bkt_src[s * BCAP + p1] = d;   // outgoing: dst ids
    int p2 = atomicAdd(&cnt_dst[d], 1);
    if (p2 < BCAP) bkt_dst[d * BCAP + p2] = s;   // incoming: src ids
    return;
  }
  int node = (blockIdx.x - FILLB) * 256 + threadIdx.x;
  if (node >= B * N) return;

  const float* hin = H + (size_t)node * F;
  float hv[F];
#pragma unroll
  for (int i = 0; i < F; i++) hv[i] = hin[i];

  float tok[3][DM];
#pragma unroll
  for (int j = 0; j < DM; j++) {
    float acc = fc_s_b[j];
#pragma unroll
    for (int i = 0; i < D_IN; i++) acc = fmaf(hv[i], fc_s_w[j * D_IN + i], acc);
    tok[0][j] = acc;
    float acc2 = fc_a_b[j];
#pragma unroll
    for (int i = 0; i < A_DIM; i++) acc2 = fmaf(hv[D_IN + i], fc_a_w[j * A_DIM + i], acc2);
    tok[1][j] = acc2;
    tok[2][j] = fmaf(hv[F - 1], fc_r_w[j], fc_r_b[j]);
  }

  float Kf[3][DM], Vf[3][DM];
#pragma unroll
  for (int t = 0; t < 3; t++) {
#pragma unroll
    for (int j = 0; j < DM; j++) {
      float ak = 0.f, av = 0.f;
#pragma unroll
      for (int d = 0; d < DM; d++) {
        ak = fmaf(tok[t][d], fuse_k_w[j * DM + d], ak);
        av = fmaf(tok[t][d], fuse_v_w[j * DM + d], av);
      }
      Kf[t][j] = ak; Vf[t][j] = av;
    }
  }

  float wbar[3] = {0.f, 0.f, 0.f};
#pragma unroll
  for (int q = 0; q < 3; q++) {
    float att[3];
#pragma unroll
    for (int t = 0; t < 3; t++) {
      float acc = 0.f;
#pragma unroll
      for (int d = 0; d < DM; d++) acc = fmaf(fuse_q[q * DM + d], Kf[t][d], acc);
      att[t] = acc * 0.25f;
    }
    float mx = fmaxf(att[0], fmaxf(att[1], att[2]));
    float e0 = expf(att[0] - mx), e1 = expf(att[1] - mx), e2 = expf(att[2] - mx);
    float inv = 1.f / (e0 + e1 + e2);
    wbar[0] += e0 * inv; wbar[1] += e1 * inv; wbar[2] += e2 * inv;
  }

  float fused[DM];
#pragma unroll
  for (int d = 0; d < DM; d++) {
    float f = (wbar[0] * Vf[0][d] + wbar[1] * Vf[1][d] + wbar[2] * Vf[2][d]) * (1.f / 3.f);
    fused[d] = fmaxf(f, 0.f);
  }

  float z[DO];
#pragma unroll
  for (int o = 0; o < DO; o++) {
    float acc = proj_b[o];
#pragma unroll
    for (int d = 0; d < DM; d++) acc = fmaf(fused[d], proj_w[o * DM + d], acc);
    z[o] = acc;
  }

  float h2[DO]; float mu = 0.f;
#pragma unroll
  for (int o = 0; o < DO; o++) {
    float acc = post_b[o];
#pragma unroll
    for (int d = 0; d < DO; d++) acc = fmaf(z[d], post_w[o * DO + d], acc);
    acc = fmaxf(acc, 0.f);
    h2[o] = acc; mu += acc;
  }
  mu *= (1.f / DO);
  float var = 0.f;
#pragma unroll
  for (int o = 0; o < DO; o++) { float dd = h2[o] - mu; var = fmaf(dd, dd, var); }
  var *= (1.f / DO);
  float rstd = rsqrtf(var + 1e-5f);
  float Hn[DO];
#pragma unroll
  for (int o = 0; o < DO; o++) Hn[o] = fmaf((h2[o] - mu) * rstd, ln_g[o], ln_b[o]);

  float* xrow = x_out + (size_t)node * (HEADS * OC);
  f4 asv;
#pragma unroll
  for (int hh = 0; hh < HEADS; hh++) {
    float as = 0.f, ad = 0.f;
#pragma unroll
    for (int oc = 0; oc < OC; oc++) {
      int k = hh * OC + oc;
      float acc = 0.f;
#pragma unroll
      for (int d = 0; d < DO; d++) acc = fmaf(Hn[d], gat_w[k * DO + d], acc);
      xrow[k] = acc;
      as = fmaf(acc, att_src[k], as);
      ad = fmaf(acc, att_dst[k], ad);
    }
    asv[hh] = as;
    advi[(size_t)node * 8 + 2 * hh] = ad;
  }
  *(f4*)(as_out + (size_t)node * HEADS) = asv;
}

// ---- per-(dst,b) softmax denominator only; 4 rows per block (b-fastest) ----
__global__ __launch_bounds__(256) void k_inv(
    const int* __restrict__ cnt_dst, const int* __restrict__ bkt_dst,
    const float* __restrict__ as_, float* __restrict__ advi) {
  int w = threadIdx.x >> 6, lane = threadIdx.x & 63;
  int r = blockIdx.x * 4 + w;
  int b = r & (B - 1), dn = r >> 4;   // same dn across waves/nearby blocks
  int deg = min(cnt_dst[dn], BCAP);
  const int* list = bkt_dst + dn * BCAP;

  const float* adp = advi + (size_t)(b * N + dn) * 8;
  float a0 = adp[0], a1 = adp[2], a2 = adp[4], a3 = adp[6];

  float sm0 = 0.f, sm1 = 0.f, sm2 = 0.f, sm3 = 0.f;
  for (int i = lane; i < deg; i += 64) {
    int s = list[i];
    f4 ap = *(const f4*)(as_ + (size_t)(b * N + s) * HEADS);
    sm0 += __expf(lrelu(ap.x + a0));
    sm1 += __expf(lrelu(ap.y + a1));
    sm2 += __expf(lrelu(ap.z + a2));
    sm3 += __expf(lrelu(ap.w + a3));
  }
#pragma unroll
  for (int off = 1; off < 64; off <<= 1) {
    sm0 += __shfl_xor(sm0, off);
    sm1 += __shfl_xor(sm1, off);
    sm2 += __shfl_xor(sm2, off);
    sm3 += __shfl_xor(sm3, off);
  }
  if (lane == 0) {
    float* ivp = advi + (size_t)(b * N + dn) * 8 + 1;
    ivp[0] = sm0 > 0.f ? 1.f / sm0 : 0.f;
    ivp[2] = sm1 > 0.f ? 1.f / sm1 : 0.f;
    ivp[4] = sm2 > 0.f ? 1.f / sm2 : 0.f;
    ivp[6] = sm3 > 0.f ? 1.f / sm3 : 0.f;
  }
}

// ---- persistent fused A+out: 2048 blocks x 8 rows (b-fastest: same s per block) ----
// LESSON (R6): DS atomics -> ds_read needs an explicit barrier; plain st/ld doesn't.
// Stores issue then drain async under next row's compute (no explicit wait needed;
// compiler guards VGPR reuse).
__global__ __launch_bounds__(256) void k_outA(
    const int* __restrict__ cnt_src, const int* __restrict__ bkt_src,
    const int* __restrict__ cnt_dst, const int* __restrict__ bkt_dst,
    const float* __restrict__ as_, const float* __restrict__ advi,
    const float* __restrict__ x_, const float* __restrict__ gat_b,
    float* __restrict__ out, float* __restrict__ A) {
  __shared__ float row[HEADS][N];
  int h = threadIdx.x >> 6, lane = threadIdx.x & 63;
  f4* rowv = (f4*)row[h];

  int r0 = blockIdx.x * ROWS_PER_BLK;
  int s = r0 >> 4;                       // same s for all 8 rows of this block
  int degO = min(cnt_src[s], BCAP);
  const int* listO = bkt_src + s * BCAP;
  int degI = min(cnt_dst[s], BCAP);
  const int* listI = bkt_dst + s * BCAP;
  float gb = gat_b[h * OC + (lane & 7)];

  for (int r = r0; r < r0 + ROWS_PER_BLK; ++r) {
    int b = r & (B - 1);

    // zero own row (wave-private)
#pragma unroll
    for (int j = 0; j < 4; j++) rowv[lane + j * 64] = (f4){0.f, 0.f, 0.f, 0.f};
    __syncthreads();

    // A accumulate over out-edges of s
    float as_h = as_[(size_t)(b * N + s) * HEADS + h];  // wave-uniform
    float rs = 0.f;
    for (int i = lane; i < degO; i += 64) {
      int d = listO[i];
      f2 rec = *(const f2*)(advi + (size_t)(b * N + d) * 8 + 2 * h);  // {ad, inv}
      float a = __expf(lrelu(as_h + rec.x)) * rec.y;
      atomicAdd(&row[h][d], a);
      rs += a;
    }
#pragma unroll
    for (int off = 1; off < 64; off <<= 1) rs += __shfl_xor(rs, off);

    // out row for node s (as dst), channels c = 8h + (lane&7); hides under A phase
    {
      f2 self = *(const f2*)(advi + (size_t)(b * N + s) * 8 + 2 * h);  // {ad, inv}
      int eslot = lane >> 3, cl = lane & 7, c = h * OC + cl;
      float acc = 0.f;
      for (int i = eslot; i < degI; i += 8) {
        int src = listI[i];
        float ex = __expf(lrelu(as_[(size_t)(b * N + src) * HEADS + h] + self.x));
        acc = fmaf(ex, x_[(size_t)(b * N + src) * (HEADS * OC) + c], acc);
      }
      acc += __shfl_xor(acc, 8);
      acc += __shfl_xor(acc, 16);
      acc += __shfl_xor(acc, 32);
      if (eslot == 0)
        out[(size_t)(b * N + s) * (HEADS * OC) + c] = acc * self.y + gb;
    }

    __syncthreads();  // REQUIRED: flush DS atomics before reading the row

    float ivr = 1.f / fmaxf(rs, 1e-9f);
    float* Arow = A + (((size_t)b * HEADS + h) * N + s) * N;
#pragma unroll
    for (int j = 0; j < 4; j++) {
      f4 v = rowv[lane + j * 64];
      v.x *= ivr; v.y *= ivr; v.z *= ivr; v.w *= ivr;
      __builtin_nontemporal_store(v, (f4*)Arow + lane + j * 64);
    }
    // no wait: stores drain under next row's zero/accumulate
  }
}

}  // namespace

extern "C" void kernel_launch(void* const* d_in, const int* in_sizes, int n_in,
                              void* d_out, int out_size, void* d_ws, size_t ws_size,
                              hipStream_t stream) {
  const float* H      = (const float*)d_in[0];
  const int*   ei     = (const int*)  d_in[1];
  const float* fc_s_w = (const float*)d_in[2];
  const float* fc_s_b = (const float*)d_in[3];
  const float* fc_a_w = (const float*)d_in[4];
  const float* fc_a_b = (const float*)d_in[5];
  const float* fc_r_w = (const float*)d_in[6];
  const float* fc_r_b = (const float*)d_in[7];
  const float* fuse_q = (const float*)d_in[8];
  const float* fuse_k_w = (const float*)d_in[9];
  const float* fuse_v_w = (const float*)d_in[10];
  const float* proj_w = (const float*)d_in[11];
  const float* proj_b = (const float*)d_in[12];
  const float* post_w = (const float*)d_in[13];
  const float* post_b = (const float*)d_in[14];
  const float* ln_g   = (const float*)d_in[15];
  const float* ln_b   = (const float*)d_in[16];
  const float* gat_w  = (const float*)d_in[17];
  const float* att_src = (const float*)d_in[18];
  const float* att_dst = (const float*)d_in[19];
  const float* gat_b  = (const float*)d_in[20];

  float* out = (float*)d_out;                        // (B,N,32)
  float* A   = out + (size_t)B * N * DO;             // (B,4,N,N)

  // ws layout
  float* ws   = (float*)d_ws;
  float* xbuf = ws;                                  // B*N*32
  float* asb  = xbuf + (size_t)B * N * (HEADS * OC); // B*N*4
  float* advi = asb + (size_t)B * N * HEADS;         // B*N*8 interleaved {ad,inv} per head
  int* ibase   = (int*)(advi + (size_t)B * N * 8);
  int* cnt_src = ibase;                 // N
  int* cnt_dst = cnt_src + N;           // N
  int* bkt_src = cnt_dst + N;           // N*BCAP (dst ids per src)
  int* bkt_dst = bkt_src + N * BCAP;    // N*BCAP (src ids per dst)

  (void)hipMemsetAsync(cnt_src, 0, 2 * N * sizeof(int), stream);
  k_prep<<<dim3(FILLB + (B * N) / 256), dim3(256), 0, stream>>>(
      ei, cnt_src, cnt_dst, bkt_src, bkt_dst,
      H, fc_s_w, fc_s_b, fc_a_w, fc_a_b, fc_r_w, fc_r_b, fuse_q, fuse_k_w,
      fuse_v_w, proj_w, proj_b, post_w, post_b, ln_g, ln_b, gat_w, att_src,
      att_dst, xbuf, asb, advi);

  k_inv<<<dim3(B * N / 4), dim3(256), 0, stream>>>(cnt_dst, bkt_dst, asb, advi);

  k_outA<<<dim3(B * N / ROWS_PER_BLK), dim3(256), 0, stream>>>(
      cnt_src, bkt_src, cnt_dst, bkt_dst, asb, advi, xbuf, gat_b, out, A);
}